// Round 5
// baseline (212.080 us; speedup 1.0000x reference)
//
#include <hip/hip_runtime.h>
#include <hip/hip_bf16.h>
#include <math.h>

// GPT-OSS MoE: rmsnorm -> gate top4 -> mxfp4 MLP1 (MFMA) -> swiglu -> mxfp4 MLP2 (MFMA) -> combine
// E=32, H=1024, I=1024, N=1024 tokens, top-4.

#define NE 32
#define HD 1024
#define ID 1024
#define NTOK 1024
#define R1 2048

typedef __attribute__((ext_vector_type(8)))  short bf16x8;
typedef __attribute__((ext_vector_type(16))) float f32x16;

// ---- workspace layout (bytes) ----
#define TB_OFF   0            // t_bf16 [1024][1024] bf16 = 2 MB
#define A_OFF    2097152      // a      [4096][1024] bf16 = 8 MB
#define YB_OFF   10485760     // yb     [4096][1024] bf16 = 8 MB
#define CNT_OFF  18874368     // counts int[32]
#define OFFS_OFF 18874624     // offsets int[33]
#define TOKL_OFF 18874880     // tok_list int[32*1024]
#define TIDX_OFF 19005952     // top_idx int[1024*4]
#define TWT_OFF  19022336     // top_wt  f32[1024*4]
#define POS_OFF  19038720     // pos_of  int[1024*4]

__device__ __forceinline__ unsigned f2bf(float f) {
    unsigned u = __float_as_uint(f);
    return (u + 0x7FFFu + ((u >> 16) & 1u)) >> 16;   // RNE
}
__device__ __forceinline__ float bf2f(unsigned u) {
    return __uint_as_float(u << 16);
}

// decode 8 fp4 elems (4 boxed int32s = 4 payload bytes = 8 nibbles) -> bf16x8,
// scale folded in as packed exponent add. fp4 zero -> ~2^-96 after scale (negligible).
__device__ __forceinline__ bf16x8 dec8(int4 wv, unsigned dd) {
    unsigned u = __builtin_amdgcn_perm((unsigned)wv.y, (unsigned)wv.x, 0x00000400u);
    unsigned v = __builtin_amdgcn_perm((unsigned)wv.w, (unsigned)wv.z, 0x04000000u);
    unsigned packed = __builtin_amdgcn_perm(v, u, 0x07060100u);   // {b0,b1,b2,b3}
    unsigned selE = packed & 0x07070707u;
    unsigned sE   = packed & 0x08080808u;
    unsigned ph   = packed >> 4;
    unsigned selO = ph & 0x07070707u;
    unsigned sO   = ph & 0x08080808u;
    const unsigned PH_hi = 0x40404040u, PH_lo = 0x3F3F3F14u;
    const unsigned PL_hi = 0xC0804000u, PL_lo = 0xC0800000u;
    unsigned hbE = __builtin_amdgcn_perm(PH_hi, PH_lo, selE) | (sE << 4);
    unsigned lbE = __builtin_amdgcn_perm(PL_hi, PL_lo, selE);
    unsigned hbO = __builtin_amdgcn_perm(PH_hi, PH_lo, selO) | (sO << 4);
    unsigned lbO = __builtin_amdgcn_perm(PL_hi, PL_lo, selO);
    unsigned mE0 = __builtin_amdgcn_perm(hbE, lbE, 0x05010400u);
    unsigned mE1 = __builtin_amdgcn_perm(hbE, lbE, 0x07030602u);
    unsigned mO0 = __builtin_amdgcn_perm(hbO, lbO, 0x05010400u);
    unsigned mO1 = __builtin_amdgcn_perm(hbO, lbO, 0x07030602u);
    unsigned r0 = __builtin_amdgcn_perm(mO0, mE0, 0x05040100u);
    unsigned r1 = __builtin_amdgcn_perm(mO0, mE0, 0x07060302u);
    unsigned r2 = __builtin_amdgcn_perm(mO1, mE1, 0x05040100u);
    unsigned r3 = __builtin_amdgcn_perm(mO1, mE1, 0x07060302u);
    unsigned o0, o1, o2, o3;
    asm("v_pk_add_u16 %0, %1, %2" : "=v"(o0) : "v"(r0), "v"(dd));
    asm("v_pk_add_u16 %0, %1, %2" : "=v"(o1) : "v"(r1), "v"(dd));
    asm("v_pk_add_u16 %0, %1, %2" : "=v"(o2) : "v"(r2), "v"(dd));
    asm("v_pk_add_u16 %0, %1, %2" : "=v"(o3) : "v"(r3), "v"(dd));
    uint4 o; o.x = o0; o.y = o1; o.z = o2; o.w = o3;
    union { uint4 u4; bf16x8 b; } cv; cv.u4 = o;
    return cv.b;
}

__device__ __forceinline__ void gll16(const void* g, void* l) {
    __builtin_amdgcn_global_load_lds(
        (const __attribute__((address_space(1))) unsigned int*)g,
        (__attribute__((address_space(3))) unsigned int*)l, 16, 0, 0);
}

__device__ __forceinline__ void fence_all() {
    asm volatile("s_waitcnt vmcnt(0) lgkmcnt(0)" ::: "memory");
    __builtin_amdgcn_sched_barrier(0);
    __builtin_amdgcn_s_barrier();
    __builtin_amdgcn_sched_barrier(0);
}

__global__ __launch_bounds__(256) void k_gate(
    const float* __restrict__ x, const float* __restrict__ norm_w,
    const float* __restrict__ gate_w, const float* __restrict__ gate_b,
    ushort* __restrict__ t_bf16, int* __restrict__ top_idx, float* __restrict__ top_wt,
    int* __restrict__ counts, int* __restrict__ tok_list, int* __restrict__ pos_of)
{
    int n = blockIdx.x;
    int tid = threadIdx.x;
    __shared__ float tl[HD];
    __shared__ float red[4];
    __shared__ float logits[NE];

    const float4* xv = (const float4*)(x + (size_t)n * HD);
    float4 v = xv[tid];
    float ss = v.x * v.x + v.y * v.y + v.z * v.z + v.w * v.w;
    #pragma unroll
    for (int off = 32; off; off >>= 1) ss += __shfl_down(ss, off);
    if ((tid & 63) == 0) red[tid >> 6] = ss;
    __syncthreads();
    float tot = red[0] + red[1] + red[2] + red[3];
    float rms = rsqrtf(tot * (1.0f / HD) + 1e-5f);

    float4 w = ((const float4*)norm_w)[tid];
    float4 tv;
    tv.x = v.x * rms * w.x; tv.y = v.y * rms * w.y;
    tv.z = v.z * rms * w.z; tv.w = v.w * rms * w.w;
    ushort4 tb;
    tb.x = (ushort)f2bf(tv.x); tb.y = (ushort)f2bf(tv.y);
    tb.z = (ushort)f2bf(tv.z); tb.w = (ushort)f2bf(tv.w);
    ((ushort4*)(t_bf16 + (size_t)n * HD))[tid] = tb;
    ((float4*)tl)[tid] = tv;
    __syncthreads();

    int wv = tid >> 6, lane = tid & 63;
    for (int j = 0; j < 8; j++) {
        int e = wv * 8 + j;
        const float* gw = gate_w + (size_t)e * HD;
        float p = 0.f;
        #pragma unroll
        for (int q = 0; q < 16; q++) { int kk = lane + q * 64; p += tl[kk] * gw[kk]; }
        #pragma unroll
        for (int off = 32; off; off >>= 1) p += __shfl_down(p, off);
        if (lane == 0) logits[e] = p + gate_b[e];
    }
    __syncthreads();

    if (tid == 0) {
        float vals[4]; int idx[4];
        unsigned used = 0;
        #pragma unroll
        for (int kk = 0; kk < 4; kk++) {
            float best = -1e30f; int bi = 0;
            for (int e2 = 0; e2 < NE; e2++) {
                if (used & (1u << e2)) continue;
                if (logits[e2] > best) { best = logits[e2]; bi = e2; }
            }
            used |= 1u << bi; vals[kk] = best; idx[kk] = bi;
        }
        float m = vals[0], s = 0.f, ex[4];
        #pragma unroll
        for (int kk = 0; kk < 4; kk++) { ex[kk] = __expf(vals[kk] - m); s += ex[kk]; }
        float inv = 1.0f / s;
        #pragma unroll
        for (int kk = 0; kk < 4; kk++) {
            top_idx[n * 4 + kk] = idx[kk];
            top_wt[n * 4 + kk] = ex[kk] * inv;
            int slot = atomicAdd(counts + idx[kk], 1);
            tok_list[idx[kk] * NTOK + slot] = n;
            pos_of[n * 4 + kk] = slot;
        }
    }
}

__global__ void k_prefix(const int* __restrict__ counts, int* __restrict__ offsets)
{
    if (threadIdx.x == 0) {
        int s = 0;
        for (int e = 0; e < NE; e++) { offsets[e] = s; s += counts[e]; }
        offsets[NE] = s;
    }
}

// MLP1 (MFMA) + swiglu. Block: expert x 128 rows x 64-token chunk (z).
// Weights: boxed bytes -> LDS via global_load_lds (coalesced, XOR-swizzled via
// pre-swizzled source), dec8 at fragment read. Tokens: reg->LDS 144B-stride tile.
// One barrier per K-step; both tiles double-buffered.
__global__ __launch_bounds__(256, 3) void k_mlp1(
    const ushort* __restrict__ t_bf16, const int* __restrict__ blocks,
    const int* __restrict__ scales, const float* __restrict__ bias,
    const int* __restrict__ counts, const int* __restrict__ offsets,
    const int* __restrict__ tok_list, ushort* __restrict__ a)
{
    int e = blockIdx.y;
    int cnt = counts[e];
    int r0 = blockIdx.x * 128;
    int tid = threadIdx.x;
    int l = tid & 63;
    int lr = l & 31, kh = l >> 5;
    int w = tid >> 6;
    int wu = __builtin_amdgcn_readfirstlane(w);
    int base = offsets[e];

    __shared__ ushort tl[2][64][72];          // 18 KB token tile (conflict-free 144B stride)
    __shared__ char   wlds[2][16384];         // 32 KB boxed-weight tile

    int row = r0 + w * 32 + lr;               // this lane's B-operand row
    const int* sp = scales + (size_t)(e * R1 + row) * 32;
    float bl = bias[e * R1 + row];
    int swzr = (lr & 7) << 4;                 // read-side XOR swizzle

    // staging source pointers: lane covers rows wu*8 + (l>>3) + j*32, 16 B at swizzled col
    int scol = ((l & 7) * 16) ^ ((l >> 3) << 4);
    const char* pw[4];
    #pragma unroll
    for (int j = 0; j < 4; j++)
        pw[j] = (const char*)blocks +
                (size_t)(e * R1 + r0 + wu * 8 + (l >> 3) + j * 32) * 2048 + scol;

    int trow = tid >> 2;                      // token staging: 4 lanes per row
    int tseg = (tid & 3) * 16;                // ushort offset within 64-elem slice

    for (int c0 = blockIdx.z * 64; c0 < cnt; c0 += 128) {
        int nt = min(64, cnt - c0);
        int nmt = (nt + 31) >> 5;
        int tok_c = trow < nt ? trow : nt - 1;
        const ushort* tp = t_bf16 + (size_t)tok_list[e * NTOK + c0 + tok_c] * HD + tseg;

        // prologue: W(0) -> wlds[0], T(0) -> tl[0]
        #pragma unroll
        for (int j = 0; j < 4; j++)
            gll16(pw[j], &wlds[0][((j << 2) + wu) << 10]);
        int2 sc = *(const int2*)sp;
        uint4 trA = *(const uint4*)tp;
        uint4 trB = *(const uint4*)(tp + 8);
        *(uint4*)&tl[0][trow][tseg] = trA;
        *(uint4*)&tl[0][trow][tseg + 8] = trB;
        fence_all();

        f32x16 acc[2] = {};
        int2 scn = sc;

        #pragma unroll 1
        for (int kt2 = 0; kt2 < 16; kt2 += 2) {
            #pragma unroll
            for (int h = 0; h < 2; h++) {
                int kt = kt2 + h;
                bool pf = kt < 15;
                if (pf) {
                    #pragma unroll
                    for (int j = 0; j < 4; j++)
                        gll16(pw[j] + (kt + 1) * 128, &wlds[h ^ 1][((j << 2) + wu) << 10]);
                    scn = *(const int2*)(sp + (kt + 1) * 2);
                    trA = *(const uint4*)(tp + (kt + 1) * 64);
                    trB = *(const uint4*)(tp + (kt + 1) * 64 + 8);
                }
                #pragma unroll
                for (int ks = 0; ks < 4; ks++) {
                    int s = ks < 2 ? sc.x : sc.y;
                    unsigned dd16 = (unsigned)((s - 127) << 7) & 0xFFFFu;
                    unsigned dd = dd16 | (dd16 << 16);
                    int4 wv = *(const int4*)&wlds[h][(w * 32 + lr) * 128 +
                                                     ((ks * 32 + kh * 16) ^ swzr)];
                    bf16x8 wf = dec8(wv, dd);
                    #pragma unroll
                    for (int mt = 0; mt < 2; mt++) {
                        if (mt < nmt) {
                            bf16x8 af = *(const bf16x8*)&tl[h][mt * 32 + lr][ks * 16 + kh * 8];
                            acc[mt] = __builtin_amdgcn_mfma_f32_32x32x16_bf16(af, wf, acc[mt], 0, 0, 0);
                        }
                    }
                }
                if (pf) {
                    *(uint4*)&tl[h ^ 1][trow][tseg] = trA;
                    *(uint4*)&tl[h ^ 1][trow][tseg + 8] = trB;
                }
                fence_all();
                sc = scn;
            }
        }

        // epilogue: bias + swiglu (glu/lin = adjacent lanes = adjacent rows)
        #pragma unroll
        for (int mt = 0; mt < 2; mt++) {
            #pragma unroll
            for (int r = 0; r < 16; r++) {
                float hv = acc[mt][r] + bl;
                float other = __shfl_xor(hv, 1, 64);
                int m = (r & 3) + 8 * (r >> 2) + 4 * kh;
                int tokg = c0 + mt * 32 + m;
                if (!(l & 1) && tokg < cnt) {
                    float hg = fminf(hv, 7.0f);
                    float hx = fminf(fmaxf(other, -7.0f), 7.0f);
                    float sig = 1.0f / (1.0f + __expf(-1.702f * hg));
                    float av = hg * sig * (hx + 1.0f);
                    a[(size_t)(base + tokg) * ID + (row >> 1)] = (ushort)f2bf(av);
                }
            }
        }
    }
}

// MLP2 (MFMA). Same pipeline; writes yb[slot][h] with bias.
__global__ __launch_bounds__(256, 3) void k_mlp2(
    const ushort* __restrict__ a, const int* __restrict__ blocks,
    const int* __restrict__ scales, const float* __restrict__ bias,
    const int* __restrict__ counts, const int* __restrict__ offsets,
    ushort* __restrict__ yb)
{
    int e = blockIdx.y;
    int cnt = counts[e];
    int r0 = blockIdx.x * 128;
    int tid = threadIdx.x;
    int l = tid & 63;
    int lr = l & 31, kh = l >> 5;
    int w = tid >> 6;
    int wu = __builtin_amdgcn_readfirstlane(w);
    int base = offsets[e];

    __shared__ ushort tl[2][64][72];
    __shared__ char   wlds[2][16384];

    int row = r0 + w * 32 + lr;
    const int* sp = scales + (size_t)(e * HD + row) * 32;
    float bl = bias[e * HD + row];
    int swzr = (lr & 7) << 4;

    int scol = ((l & 7) * 16) ^ ((l >> 3) << 4);
    const char* pw[4];
    #pragma unroll
    for (int j = 0; j < 4; j++)
        pw[j] = (const char*)blocks +
                (size_t)(e * HD + r0 + wu * 8 + (l >> 3) + j * 32) * 2048 + scol;

    int trow = tid >> 2;
    int tseg = (tid & 3) * 16;

    for (int c0 = blockIdx.z * 64; c0 < cnt; c0 += 128) {
        int nt = min(64, cnt - c0);
        int nmt = (nt + 31) >> 5;
        int tok_c = trow < nt ? trow : nt - 1;
        const ushort* tp = a + (size_t)(base + c0 + tok_c) * ID + tseg;

        #pragma unroll
        for (int j = 0; j < 4; j++)
            gll16(pw[j], &wlds[0][((j << 2) + wu) << 10]);
        int2 sc = *(const int2*)sp;
        uint4 trA = *(const uint4*)tp;
        uint4 trB = *(const uint4*)(tp + 8);
        *(uint4*)&tl[0][trow][tseg] = trA;
        *(uint4*)&tl[0][trow][tseg + 8] = trB;
        fence_all();

        f32x16 acc[2] = {};
        int2 scn = sc;

        #pragma unroll 1
        for (int kt2 = 0; kt2 < 16; kt2 += 2) {
            #pragma unroll
            for (int h = 0; h < 2; h++) {
                int kt = kt2 + h;
                bool pf = kt < 15;
                if (pf) {
                    #pragma unroll
                    for (int j = 0; j < 4; j++)
                        gll16(pw[j] + (kt + 1) * 128, &wlds[h ^ 1][((j << 2) + wu) << 10]);
                    scn = *(const int2*)(sp + (kt + 1) * 2);
                    trA = *(const uint4*)(tp + (kt + 1) * 64);
                    trB = *(const uint4*)(tp + (kt + 1) * 64 + 8);
                }
                #pragma unroll
                for (int ks = 0; ks < 4; ks++) {
                    int s = ks < 2 ? sc.x : sc.y;
                    unsigned dd16 = (unsigned)((s - 127) << 7) & 0xFFFFu;
                    unsigned dd = dd16 | (dd16 << 16);
                    int4 wv = *(const int4*)&wlds[h][(w * 32 + lr) * 128 +
                                                     ((ks * 32 + kh * 16) ^ swzr)];
                    bf16x8 wf = dec8(wv, dd);
                    #pragma unroll
                    for (int mt = 0; mt < 2; mt++) {
                        if (mt < nmt) {
                            bf16x8 af = *(const bf16x8*)&tl[h][mt * 32 + lr][ks * 16 + kh * 8];
                            acc[mt] = __builtin_amdgcn_mfma_f32_32x32x16_bf16(af, wf, acc[mt], 0, 0, 0);
                        }
                    }
                }
                if (pf) {
                    *(uint4*)&tl[h ^ 1][trow][tseg] = trA;
                    *(uint4*)&tl[h ^ 1][trow][tseg + 8] = trB;
                }
                fence_all();
                sc = scn;
            }
        }

        #pragma unroll
        for (int mt = 0; mt < 2; mt++) {
            #pragma unroll
            for (int r = 0; r < 16; r++) {
                int m = (r & 3) + 8 * (r >> 2) + 4 * kh;
                int tokg = c0 + mt * 32 + m;
                if (tokg < cnt) {
                    float y = acc[mt][r] + bl;
                    yb[(size_t)(base + tokg) * HD + row] = (ushort)f2bf(y);
                }
            }
        }
    }
}

__global__ __launch_bounds__(256) void k_combine(
    const float* __restrict__ x, const ushort* __restrict__ yb,
    const int* __restrict__ top_idx, const float* __restrict__ top_wt,
    const int* __restrict__ pos_of, const int* __restrict__ offsets,
    float* __restrict__ out)
{
    int n = blockIdx.x, tid = threadIdx.x;
    float4 xv = ((const float4*)(x + (size_t)n * HD))[tid];
    float r0 = xv.x, r1 = xv.y, r2 = xv.z, r3 = xv.w;
    #pragma unroll
    for (int k = 0; k < 4; k++) {
        int e = top_idx[n * 4 + k];
        float wt = top_wt[n * 4 + k];
        int slot = offsets[e] + pos_of[n * 4 + k];
        ushort4 yv = ((const ushort4*)(yb + (size_t)slot * HD))[tid];
        r0 += wt * bf2f(yv.x); r1 += wt * bf2f(yv.y);
        r2 += wt * bf2f(yv.z); r3 += wt * bf2f(yv.w);
    }
    float4 ov; ov.x = r0; ov.y = r1; ov.z = r2; ov.w = r3;
    ((float4*)(out + (size_t)n * HD))[tid] = ov;
}

extern "C" void kernel_launch(void* const* d_in, const int* in_sizes, int n_in,
                              void* d_out, int out_size, void* d_ws, size_t ws_size,
                              hipStream_t stream)
{
    const float* x           = (const float*)d_in[0];
    const float* norm_w      = (const float*)d_in[1];
    const float* gate_w      = (const float*)d_in[2];
    const float* gate_b      = (const float*)d_in[3];
    const float* mlp1_bias   = (const float*)d_in[4];
    const float* mlp2_bias   = (const float*)d_in[5];
    const int*   mlp1_blocks = (const int*)d_in[6];
    const int*   mlp1_scales = (const int*)d_in[7];
    const int*   mlp2_blocks = (const int*)d_in[8];
    const int*   mlp2_scales = (const int*)d_in[9];
    float* out = (float*)d_out;

    char* ws = (char*)d_ws;
    ushort* t_bf16  = (ushort*)(ws + TB_OFF);
    ushort* a       = (ushort*)(ws + A_OFF);
    ushort* yb      = (ushort*)(ws + YB_OFF);
    int*   counts   = (int*)(ws + CNT_OFF);
    int*   offsets  = (int*)(ws + OFFS_OFF);
    int*   tok_list = (int*)(ws + TOKL_OFF);
    int*   top_idx  = (int*)(ws + TIDX_OFF);
    float* top_wt   = (float*)(ws + TWT_OFF);
    int*   pos_of   = (int*)(ws + POS_OFF);

    hipMemsetAsync(counts, 0, NE * sizeof(int), stream);
    k_gate<<<NTOK, 256, 0, stream>>>(x, norm_w, gate_w, gate_b, t_bf16, top_idx, top_wt,
                                     counts, tok_list, pos_of);
    k_prefix<<<1, 64, 0, stream>>>(counts, offsets);
    k_mlp1<<<dim3(16, NE, 2), 256, 0, stream>>>(t_bf16, mlp1_blocks, mlp1_scales, mlp1_bias,
                                                counts, offsets, tok_list, a);
    k_mlp2<<<dim3(8, NE, 2), 256, 0, stream>>>(a, mlp2_blocks, mlp2_scales, mlp2_bias,
                                               counts, offsets, yb);
    k_combine<<<NTOK, 256, 0, stream>>>(x, yb, top_idx, top_wt, pos_of, offsets, out);
}

// Round 6
// 171.456 us; speedup vs baseline: 1.2369x; 1.2369x over previous
//
#include <hip/hip_runtime.h>
#include <hip/hip_bf16.h>
#include <math.h>

// GPT-OSS MoE: rmsnorm -> gate top4 -> mxfp4 MLP1 (MFMA) -> swiglu -> mxfp4 MLP2 (MFMA) -> combine
// E=32, H=1024, I=1024, N=1024 tokens, top-4.

#define NE 32
#define HD 1024
#define ID 1024
#define NTOK 1024
#define R1 2048

typedef __attribute__((ext_vector_type(8)))  short bf16x8;
typedef __attribute__((ext_vector_type(16))) float f32x16;

// ---- workspace layout (bytes) ----
#define TB_OFF   0            // t_bf16 [1024][1024] bf16 = 2 MB
#define A_OFF    2097152      // a      [4096][1024] bf16 = 8 MB
#define YB_OFF   10485760     // yb     [4096][1024] bf16 = 8 MB
#define CNT_OFF  18874368     // counts int[32]
#define OFFS_OFF 18874624     // offsets int[33]
#define TOKL_OFF 18874880     // tok_list int[32*1024]
#define TIDX_OFF 19005952     // top_idx int[1024*4]
#define TWT_OFF  19022336     // top_wt  f32[1024*4]
#define POS_OFF  19038720     // pos_of  int[1024*4]

__device__ __forceinline__ unsigned f2bf(float f) {
    unsigned u = __float_as_uint(f);
    return (u + 0x7FFFu + ((u >> 16) & 1u)) >> 16;   // RNE
}
__device__ __forceinline__ float bf2f(unsigned u) {
    return __uint_as_float(u << 16);
}

// decode 8 fp4 elems (4 boxed int32s = 4 payload bytes = 8 nibbles) -> bf16x8,
// scale folded in as packed exponent add. fp4 zero -> ~2^-96 after scale (negligible).
__device__ __forceinline__ bf16x8 dec8(int4 wv, unsigned dd) {
    unsigned u = __builtin_amdgcn_perm((unsigned)wv.y, (unsigned)wv.x, 0x00000400u);
    unsigned v = __builtin_amdgcn_perm((unsigned)wv.w, (unsigned)wv.z, 0x04000000u);
    unsigned packed = __builtin_amdgcn_perm(v, u, 0x07060100u);   // {b0,b1,b2,b3}
    unsigned selE = packed & 0x07070707u;
    unsigned sE   = packed & 0x08080808u;
    unsigned ph   = packed >> 4;
    unsigned selO = ph & 0x07070707u;
    unsigned sO   = ph & 0x08080808u;
    const unsigned PH_hi = 0x40404040u, PH_lo = 0x3F3F3F14u;
    const unsigned PL_hi = 0xC0804000u, PL_lo = 0xC0800000u;
    unsigned hbE = __builtin_amdgcn_perm(PH_hi, PH_lo, selE) | (sE << 4);
    unsigned lbE = __builtin_amdgcn_perm(PL_hi, PL_lo, selE);
    unsigned hbO = __builtin_amdgcn_perm(PH_hi, PH_lo, selO) | (sO << 4);
    unsigned lbO = __builtin_amdgcn_perm(PL_hi, PL_lo, selO);
    unsigned mE0 = __builtin_amdgcn_perm(hbE, lbE, 0x05010400u);
    unsigned mE1 = __builtin_amdgcn_perm(hbE, lbE, 0x07030602u);
    unsigned mO0 = __builtin_amdgcn_perm(hbO, lbO, 0x05010400u);
    unsigned mO1 = __builtin_amdgcn_perm(hbO, lbO, 0x07030602u);
    unsigned r0 = __builtin_amdgcn_perm(mO0, mE0, 0x05040100u);
    unsigned r1 = __builtin_amdgcn_perm(mO0, mE0, 0x07060302u);
    unsigned r2 = __builtin_amdgcn_perm(mO1, mE1, 0x05040100u);
    unsigned r3 = __builtin_amdgcn_perm(mO1, mE1, 0x07060302u);
    unsigned o0, o1, o2, o3;
    asm("v_pk_add_u16 %0, %1, %2" : "=v"(o0) : "v"(r0), "v"(dd));
    asm("v_pk_add_u16 %0, %1, %2" : "=v"(o1) : "v"(r1), "v"(dd));
    asm("v_pk_add_u16 %0, %1, %2" : "=v"(o2) : "v"(r2), "v"(dd));
    asm("v_pk_add_u16 %0, %1, %2" : "=v"(o3) : "v"(r3), "v"(dd));
    uint4 o; o.x = o0; o.y = o1; o.z = o2; o.w = o3;
    union { uint4 u4; bf16x8 b; } cv; cv.u4 = o;
    return cv.b;
}

__device__ __forceinline__ void gll16(const void* g, void* l) {
    __builtin_amdgcn_global_load_lds(
        (const __attribute__((address_space(1))) unsigned int*)g,
        (__attribute__((address_space(3))) unsigned int*)l, 16, 0, 0);
}

__device__ __forceinline__ void fence_all() {
    asm volatile("s_waitcnt vmcnt(0) lgkmcnt(0)" ::: "memory");
    __builtin_amdgcn_sched_barrier(0);
    __builtin_amdgcn_s_barrier();
    __builtin_amdgcn_sched_barrier(0);
}

__global__ __launch_bounds__(256) void k_gate(
    const float* __restrict__ x, const float* __restrict__ norm_w,
    const float* __restrict__ gate_w, const float* __restrict__ gate_b,
    ushort* __restrict__ t_bf16, int* __restrict__ top_idx, float* __restrict__ top_wt,
    int* __restrict__ counts, int* __restrict__ tok_list, int* __restrict__ pos_of)
{
    int n = blockIdx.x;
    int tid = threadIdx.x;
    __shared__ float tl[HD];
    __shared__ float red[4];
    __shared__ float logits[NE];

    const float4* xv = (const float4*)(x + (size_t)n * HD);
    float4 v = xv[tid];
    float ss = v.x * v.x + v.y * v.y + v.z * v.z + v.w * v.w;
    #pragma unroll
    for (int off = 32; off; off >>= 1) ss += __shfl_down(ss, off);
    if ((tid & 63) == 0) red[tid >> 6] = ss;
    __syncthreads();
    float tot = red[0] + red[1] + red[2] + red[3];
    float rms = rsqrtf(tot * (1.0f / HD) + 1e-5f);

    float4 w = ((const float4*)norm_w)[tid];
    float4 tv;
    tv.x = v.x * rms * w.x; tv.y = v.y * rms * w.y;
    tv.z = v.z * rms * w.z; tv.w = v.w * rms * w.w;
    ushort4 tb;
    tb.x = (ushort)f2bf(tv.x); tb.y = (ushort)f2bf(tv.y);
    tb.z = (ushort)f2bf(tv.z); tb.w = (ushort)f2bf(tv.w);
    ((ushort4*)(t_bf16 + (size_t)n * HD))[tid] = tb;
    ((float4*)tl)[tid] = tv;
    __syncthreads();

    int wv = tid >> 6, lane = tid & 63;
    for (int j = 0; j < 8; j++) {
        int e = wv * 8 + j;
        const float* gw = gate_w + (size_t)e * HD;
        float p = 0.f;
        #pragma unroll
        for (int q = 0; q < 16; q++) { int kk = lane + q * 64; p += tl[kk] * gw[kk]; }
        #pragma unroll
        for (int off = 32; off; off >>= 1) p += __shfl_down(p, off);
        if (lane == 0) logits[e] = p + gate_b[e];
    }
    __syncthreads();

    if (tid == 0) {
        float vals[4]; int idx[4];
        unsigned used = 0;
        #pragma unroll
        for (int kk = 0; kk < 4; kk++) {
            float best = -1e30f; int bi = 0;
            for (int e2 = 0; e2 < NE; e2++) {
                if (used & (1u << e2)) continue;
                if (logits[e2] > best) { best = logits[e2]; bi = e2; }
            }
            used |= 1u << bi; vals[kk] = best; idx[kk] = bi;
        }
        float m = vals[0], s = 0.f, ex[4];
        #pragma unroll
        for (int kk = 0; kk < 4; kk++) { ex[kk] = __expf(vals[kk] - m); s += ex[kk]; }
        float inv = 1.0f / s;
        #pragma unroll
        for (int kk = 0; kk < 4; kk++) {
            top_idx[n * 4 + kk] = idx[kk];
            top_wt[n * 4 + kk] = ex[kk] * inv;
            int slot = atomicAdd(counts + idx[kk], 1);
            tok_list[idx[kk] * NTOK + slot] = n;
            pos_of[n * 4 + kk] = slot;
        }
    }
}

__global__ void k_prefix(const int* __restrict__ counts, int* __restrict__ offsets)
{
    if (threadIdx.x == 0) {
        int s = 0;
        for (int e = 0; e < NE; e++) { offsets[e] = s; s += counts[e]; }
        offsets[NE] = s;
    }
}

// MLP1 (MFMA) + swiglu. Block: expert x 128 rows x up-to-128 tokens.
// Weights: boxed bytes -> LDS via global_load_lds (XOR-swizzled via pre-swizzled
// source), dec8 at fragment read. Tokens: SoA LDS tile [slot][token][8] --
// conflict-free writes AND reads. One fence per K-step, double-buffered.
__global__ __launch_bounds__(256, 2) void k_mlp1(
    const ushort* __restrict__ t_bf16, const int* __restrict__ blocks,
    const int* __restrict__ scales, const float* __restrict__ bias,
    const int* __restrict__ counts, const int* __restrict__ offsets,
    const int* __restrict__ tok_list, ushort* __restrict__ a)
{
    int e = blockIdx.y;
    int cnt = counts[e];
    if (cnt == 0) return;
    int r0 = blockIdx.x * 128;
    int tid = threadIdx.x;
    int l = tid & 63;
    int lr = l & 31, kh = l >> 5;
    int w = tid >> 6;
    int wu = __builtin_amdgcn_readfirstlane(w);
    int base = offsets[e];

    __shared__ ushort tsoa[2][8][128][8];     // 32 KB token tile (SoA, conflict-free)
    __shared__ char   wlds[2][16384];         // 32 KB boxed-weight tile

    int row = r0 + w * 32 + lr;               // this lane's B-operand row
    const int* sp = scales + (size_t)(e * R1 + row) * 32;
    float bl = bias[e * R1 + row];
    int swzr = (lr & 7) << 4;                 // read-side XOR swizzle

    // weight staging: lane covers rows j*32 + wu*8 + (l>>3), 16 B at swizzled col
    int scol = ((l & 7) * 16) ^ ((l >> 3) << 4);
    const char* pw[4];
    #pragma unroll
    for (int j = 0; j < 4; j++)
        pw[j] = (const char*)blocks +
                (size_t)(e * R1 + r0 + j * 32 + wu * 8 + (l >> 3)) * 2048 + scol;

    // token staging: thread covers token tk, slots sbase..sbase+3 (8 ushorts each)
    int tk = w * 32 + (l & 31);
    int sbase = (l >> 5) * 4;

    for (int c0 = 0; c0 < cnt; c0 += 128) {
        int nt = min(128, cnt - c0);
        int nmt = (nt + 31) >> 5;
        const ushort* tokp = t_bf16 +
            (size_t)tok_list[e * NTOK + c0 + min(tk, nt - 1)] * HD + sbase * 8;

        // prologue: tokens(0) -> regs, W(0) -> wlds[0], tokens -> tsoa[0]
        uint4 ta = *(const uint4*)(tokp);
        uint4 tb = *(const uint4*)(tokp + 8);
        uint4 tc = *(const uint4*)(tokp + 16);
        uint4 td = *(const uint4*)(tokp + 24);
        #pragma unroll
        for (int j = 0; j < 4; j++)
            gll16(pw[j], &wlds[0][((j << 2) + wu) << 10]);
        int2 sc = *(const int2*)sp;
        *(uint4*)&tsoa[0][sbase + 0][tk][0] = ta;
        *(uint4*)&tsoa[0][sbase + 1][tk][0] = tb;
        *(uint4*)&tsoa[0][sbase + 2][tk][0] = tc;
        *(uint4*)&tsoa[0][sbase + 3][tk][0] = td;
        fence_all();

        f32x16 acc[4] = {};
        int2 scn = sc;

        #pragma unroll 1
        for (int kt2 = 0; kt2 < 16; kt2 += 2) {
            #pragma unroll
            for (int h = 0; h < 2; h++) {
                int kt = kt2 + h;
                bool pf = kt < 15;
                if (pf) {
                    const ushort* tpk = tokp + (kt + 1) * 64;
                    ta = *(const uint4*)(tpk);
                    tb = *(const uint4*)(tpk + 8);
                    tc = *(const uint4*)(tpk + 16);
                    td = *(const uint4*)(tpk + 24);
                    #pragma unroll
                    for (int j = 0; j < 4; j++)
                        gll16(pw[j] + (kt + 1) * 128, &wlds[h ^ 1][((j << 2) + wu) << 10]);
                    scn = *(const int2*)(sp + (kt + 1) * 2);
                    __builtin_amdgcn_sched_barrier(0);
                }
                #pragma unroll
                for (int ks = 0; ks < 4; ks++) {
                    int s = ks < 2 ? sc.x : sc.y;
                    unsigned dd16 = (unsigned)((s - 127) << 7) & 0xFFFFu;
                    unsigned dd = dd16 | (dd16 << 16);
                    int4 wv = *(const int4*)&wlds[h][(w * 32 + lr) * 128 +
                                                     ((ks * 32 + kh * 16) ^ swzr)];
                    bf16x8 wf = dec8(wv, dd);
                    #pragma unroll
                    for (int mt = 0; mt < 4; mt++) {
                        if (mt < nmt) {
                            bf16x8 af = *(const bf16x8*)&tsoa[h][ks * 2 + kh][mt * 32 + lr][0];
                            acc[mt] = __builtin_amdgcn_mfma_f32_32x32x16_bf16(af, wf, acc[mt], 0, 0, 0);
                        }
                    }
                }
                if (pf) {
                    *(uint4*)&tsoa[h ^ 1][sbase + 0][tk][0] = ta;
                    *(uint4*)&tsoa[h ^ 1][sbase + 1][tk][0] = tb;
                    *(uint4*)&tsoa[h ^ 1][sbase + 2][tk][0] = tc;
                    *(uint4*)&tsoa[h ^ 1][sbase + 3][tk][0] = td;
                }
                fence_all();
                sc = scn;
            }
        }

        // epilogue: bias + swiglu (glu/lin = adjacent lanes = adjacent rows)
        #pragma unroll
        for (int mt = 0; mt < 4; mt++) {
            if (mt >= nmt) break;
            #pragma unroll
            for (int r = 0; r < 16; r++) {
                float hv = acc[mt][r] + bl;
                float other = __shfl_xor(hv, 1, 64);
                int m = (r & 3) + 8 * (r >> 2) + 4 * kh;
                int tokg = c0 + mt * 32 + m;
                if (!(l & 1) && tokg < cnt) {
                    float hg = fminf(hv, 7.0f);
                    float hx = fminf(fmaxf(other, -7.0f), 7.0f);
                    float sig = 1.0f / (1.0f + __expf(-1.702f * hg));
                    float av = hg * sig * (hx + 1.0f);
                    a[(size_t)(base + tokg) * ID + (row >> 1)] = (ushort)f2bf(av);
                }
            }
        }
    }
}

// MLP2 (MFMA). Same pipeline; writes yb[slot][h] with bias.
__global__ __launch_bounds__(256, 2) void k_mlp2(
    const ushort* __restrict__ a, const int* __restrict__ blocks,
    const int* __restrict__ scales, const float* __restrict__ bias,
    const int* __restrict__ counts, const int* __restrict__ offsets,
    ushort* __restrict__ yb)
{
    int e = blockIdx.y;
    int cnt = counts[e];
    if (cnt == 0) return;
    int r0 = blockIdx.x * 128;
    int tid = threadIdx.x;
    int l = tid & 63;
    int lr = l & 31, kh = l >> 5;
    int w = tid >> 6;
    int wu = __builtin_amdgcn_readfirstlane(w);
    int base = offsets[e];

    __shared__ ushort tsoa[2][8][128][8];
    __shared__ char   wlds[2][16384];

    int row = r0 + w * 32 + lr;
    const int* sp = scales + (size_t)(e * HD + row) * 32;
    float bl = bias[e * HD + row];
    int swzr = (lr & 7) << 4;

    int scol = ((l & 7) * 16) ^ ((l >> 3) << 4);
    const char* pw[4];
    #pragma unroll
    for (int j = 0; j < 4; j++)
        pw[j] = (const char*)blocks +
                (size_t)(e * HD + r0 + j * 32 + wu * 8 + (l >> 3)) * 2048 + scol;

    int tk = w * 32 + (l & 31);
    int sbase = (l >> 5) * 4;

    for (int c0 = 0; c0 < cnt; c0 += 128) {
        int nt = min(128, cnt - c0);
        int nmt = (nt + 31) >> 5;
        const ushort* tokp = a + (size_t)(base + c0 + min(tk, nt - 1)) * ID + sbase * 8;

        uint4 ta = *(const uint4*)(tokp);
        uint4 tb = *(const uint4*)(tokp + 8);
        uint4 tc = *(const uint4*)(tokp + 16);
        uint4 td = *(const uint4*)(tokp + 24);
        #pragma unroll
        for (int j = 0; j < 4; j++)
            gll16(pw[j], &wlds[0][((j << 2) + wu) << 10]);
        int2 sc = *(const int2*)sp;
        *(uint4*)&tsoa[0][sbase + 0][tk][0] = ta;
        *(uint4*)&tsoa[0][sbase + 1][tk][0] = tb;
        *(uint4*)&tsoa[0][sbase + 2][tk][0] = tc;
        *(uint4*)&tsoa[0][sbase + 3][tk][0] = td;
        fence_all();

        f32x16 acc[4] = {};
        int2 scn = sc;

        #pragma unroll 1
        for (int kt2 = 0; kt2 < 16; kt2 += 2) {
            #pragma unroll
            for (int h = 0; h < 2; h++) {
                int kt = kt2 + h;
                bool pf = kt < 15;
                if (pf) {
                    const ushort* tpk = tokp + (kt + 1) * 64;
                    ta = *(const uint4*)(tpk);
                    tb = *(const uint4*)(tpk + 8);
                    tc = *(const uint4*)(tpk + 16);
                    td = *(const uint4*)(tpk + 24);
                    #pragma unroll
                    for (int j = 0; j < 4; j++)
                        gll16(pw[j] + (kt + 1) * 128, &wlds[h ^ 1][((j << 2) + wu) << 10]);
                    scn = *(const int2*)(sp + (kt + 1) * 2);
                    __builtin_amdgcn_sched_barrier(0);
                }
                #pragma unroll
                for (int ks = 0; ks < 4; ks++) {
                    int s = ks < 2 ? sc.x : sc.y;
                    unsigned dd16 = (unsigned)((s - 127) << 7) & 0xFFFFu;
                    unsigned dd = dd16 | (dd16 << 16);
                    int4 wv = *(const int4*)&wlds[h][(w * 32 + lr) * 128 +
                                                     ((ks * 32 + kh * 16) ^ swzr)];
                    bf16x8 wf = dec8(wv, dd);
                    #pragma unroll
                    for (int mt = 0; mt < 4; mt++) {
                        if (mt < nmt) {
                            bf16x8 af = *(const bf16x8*)&tsoa[h][ks * 2 + kh][mt * 32 + lr][0];
                            acc[mt] = __builtin_amdgcn_mfma_f32_32x32x16_bf16(af, wf, acc[mt], 0, 0, 0);
                        }
                    }
                }
                if (pf) {
                    *(uint4*)&tsoa[h ^ 1][sbase + 0][tk][0] = ta;
                    *(uint4*)&tsoa[h ^ 1][sbase + 1][tk][0] = tb;
                    *(uint4*)&tsoa[h ^ 1][sbase + 2][tk][0] = tc;
                    *(uint4*)&tsoa[h ^ 1][sbase + 3][tk][0] = td;
                }
                fence_all();
                sc = scn;
            }
        }

        #pragma unroll
        for (int mt = 0; mt < 4; mt++) {
            if (mt >= nmt) break;
            #pragma unroll
            for (int r = 0; r < 16; r++) {
                int m = (r & 3) + 8 * (r >> 2) + 4 * kh;
                int tokg = c0 + mt * 32 + m;
                if (tokg < cnt) {
                    float y = acc[mt][r] + bl;
                    yb[(size_t)(base + tokg) * HD + row] = (ushort)f2bf(y);
                }
            }
        }
    }
}

__global__ __launch_bounds__(256) void k_combine(
    const float* __restrict__ x, const ushort* __restrict__ yb,
    const int* __restrict__ top_idx, const float* __restrict__ top_wt,
    const int* __restrict__ pos_of, const int* __restrict__ offsets,
    float* __restrict__ out)
{
    int n = blockIdx.x, tid = threadIdx.x;
    float4 xv = ((const float4*)(x + (size_t)n * HD))[tid];
    float r0 = xv.x, r1 = xv.y, r2 = xv.z, r3 = xv.w;
    #pragma unroll
    for (int k = 0; k < 4; k++) {
        int e = top_idx[n * 4 + k];
        float wt = top_wt[n * 4 + k];
        int slot = offsets[e] + pos_of[n * 4 + k];
        ushort4 yv = ((const ushort4*)(yb + (size_t)slot * HD))[tid];
        r0 += wt * bf2f(yv.x); r1 += wt * bf2f(yv.y);
        r2 += wt * bf2f(yv.z); r3 += wt * bf2f(yv.w);
    }
    float4 ov; ov.x = r0; ov.y = r1; ov.z = r2; ov.w = r3;
    ((float4*)(out + (size_t)n * HD))[tid] = ov;
}

extern "C" void kernel_launch(void* const* d_in, const int* in_sizes, int n_in,
                              void* d_out, int out_size, void* d_ws, size_t ws_size,
                              hipStream_t stream)
{
    const float* x           = (const float*)d_in[0];
    const float* norm_w      = (const float*)d_in[1];
    const float* gate_w      = (const float*)d_in[2];
    const float* gate_b      = (const float*)d_in[3];
    const float* mlp1_bias   = (const float*)d_in[4];
    const float* mlp2_bias   = (const float*)d_in[5];
    const int*   mlp1_blocks = (const int*)d_in[6];
    const int*   mlp1_scales = (const int*)d_in[7];
    const int*   mlp2_blocks = (const int*)d_in[8];
    const int*   mlp2_scales = (const int*)d_in[9];
    float* out = (float*)d_out;

    char* ws = (char*)d_ws;
    ushort* t_bf16  = (ushort*)(ws + TB_OFF);
    ushort* a       = (ushort*)(ws + A_OFF);
    ushort* yb      = (ushort*)(ws + YB_OFF);
    int*   counts   = (int*)(ws + CNT_OFF);
    int*   offsets  = (int*)(ws + OFFS_OFF);
    int*   tok_list = (int*)(ws + TOKL_OFF);
    int*   top_idx  = (int*)(ws + TIDX_OFF);
    float* top_wt   = (float*)(ws + TWT_OFF);
    int*   pos_of   = (int*)(ws + POS_OFF);

    hipMemsetAsync(counts, 0, NE * sizeof(int), stream);
    k_gate<<<NTOK, 256, 0, stream>>>(x, norm_w, gate_w, gate_b, t_bf16, top_idx, top_wt,
                                     counts, tok_list, pos_of);
    k_prefix<<<1, 64, 0, stream>>>(counts, offsets);
    k_mlp1<<<dim3(16, NE), 256, 0, stream>>>(t_bf16, mlp1_blocks, mlp1_scales, mlp1_bias,
                                             counts, offsets, tok_list, a);
    k_mlp2<<<dim3(8, NE), 256, 0, stream>>>(a, mlp2_blocks, mlp2_scales, mlp2_bias,
                                            counts, offsets, yb);
    k_combine<<<NTOK, 256, 0, stream>>>(x, yb, top_idx, top_wt, pos_of, offsets, out);
}